// Round 9
// baseline (96.269 us; speedup 1.0000x reference)
//
#include <hip/hip_runtime.h>
#include <cstdint>

#define N_NODES 8192
#define DIN 128
#define DOUT 128
#define MAXDEG 128                               // Poisson(32): P(deg>128) ~ 1e-18
#define EPS 1e-8f

#define NB 256                                   // buckets == build blocks
#define BROWS 32                                 // adjacency rows per bucket/build block
#define WPR 256                                  // u32 words per adjacency row (8192/32)
#define SCB 128                                  // scatter blocks
#define BCAP 64                                  // slots per (scatter block, bucket); mean 16
#define STAGE_WORDS (NB * BCAP)                  // 16384 u32 = 64 KB LDS stage
#define XW_ROWS 64                               // rows per xw block
#define XWB (N_NODES / XW_ROWS)                  // 128 xw blocks

// workspace layout (bytes):
// [dis 32K][deg 32K][list 2M][z16 2M][cnt 128K][bucket 8M]
#define OFF_DEG   (N_NODES * 4)
#define OFF_LIST  (OFF_DEG + N_NODES * 4)
#define OFF_Z16   (OFF_LIST + N_NODES * MAXDEG * 2)
#define OFF_CNT   (OFF_Z16 + N_NODES * DOUT * 2)
#define OFF_BUCK  (OFF_CNT + SCB * NB * 4)

static __device__ __forceinline__ uint16_t f2bf(float f) {
    uint32_t u = __float_as_uint(f);
    return (uint16_t)((u + 0x7fffu + ((u >> 16) & 1u)) >> 16);   // RNE
}
static __device__ __forceinline__ float bf2f(uint32_t bits16) {
    return __uint_as_float(bits16 << 16);
}

// ---------------------------------------------------------------------------
// Kernel 1 (512 thr): blocks [0,128): edge bucket-scatter, LDS-staged
//   (R7-proven: rank via LDS atomicAdd into [256][64] stage; coalesced
//   64 KB flush to bucket[sb][bucket][slot]; garbage masked by cnt).
// blocks [128,256): z16 = bf16(x @ W^T), 64 rows per block, 4 column-teams
//   of 128 doing 16 rows each (R2-proven shape: halves W L2 traffic and
//   ds_read-per-FMA vs the 8/4-row variants).
// ---------------------------------------------------------------------------
__global__ __launch_bounds__(512) void gcn_scatter_xw(const int* __restrict__ ei, int E,
                                                      const float* __restrict__ x,
                                                      const float* __restrict__ W,
                                                      uint16_t* __restrict__ z16,
                                                      uint32_t* __restrict__ cnt,
                                                      uint32_t* __restrict__ bucket) {
    __shared__ uint32_t shbuf[STAGE_WORDS + NB];     // 64 KB stage | 1 KB hist
    int t = threadIdx.x;

    if ((int)blockIdx.x < SCB) {
        // ---------------- scatter role (R7 verbatim) ----------------
        int sb = blockIdx.x;
        uint32_t* stage = shbuf;                     // [NB][BCAP]
        uint32_t* hist  = shbuf + STAGE_WORDS;       // [NB]
        if (t < NB) hist[t] = 0;
        __syncthreads();

        const int4* s4 = (const int4*)ei;
        const int4* d4 = (const int4*)(ei + E);
        int nIter = E >> 2;

#define SC1(ss, dd) do { unsigned b_ = ((unsigned)(ss)) >> 5;                              \
            unsigned r_ = atomicAdd(&hist[b_], 1u);                                        \
            if (r_ < BCAP) stage[(b_ << 6) + r_] =                                         \
                (((unsigned)(ss) & 31u) << 13) | (unsigned)(dd); } while (0)

        for (int g = sb * 512 + t; g < nIter; g += SCB * 512) {   // exactly 1 iter here
            int4 vs = s4[g], vd = d4[g];
            SC1(vs.x, vd.x); SC1(vs.y, vd.y); SC1(vs.z, vd.z); SC1(vs.w, vd.w);
        }
        if (sb == 0) {                                            // scalar tail (E % 4)
            for (int i = (nIter << 2) + t; i < E; i += 512) {
                int ss = ei[i], dd = ei[E + i];
                SC1(ss, dd);
            }
        }
#undef SC1
        __syncthreads();

        // coalesced 64 KB flush: bucket[sb * 16384 + s], s linear
        const uint4* st4 = (const uint4*)stage;
        uint4* gb4 = (uint4*)(bucket + ((size_t)sb << 14));
        for (int i = t; i < STAGE_WORDS / 4; i += 512)
            gb4[i] = st4[i];
        if (t < NB) cnt[(sb << 8) + t] = hist[t];
        return;
    }

    // ---------------- xw role: 4 column-teams of 128; team does 16 rows ----
    int bb = blockIdx.x - SCB;
    int col = t & 127;
    int team = t >> 7;                               // 0..3
    int row0 = bb * XW_ROWS + team * 16;
    float* xl = (float*)shbuf;                       // [64][128] = 32 KB subset

    for (int rr = 0; rr < 16; rr++)
        xl[(team * 16 + rr) * DIN + col] = x[(size_t)(row0 + rr) * DIN + col];
    __syncthreads();

    float acc[16];
#pragma unroll
    for (int rr = 0; rr < 16; rr++) acc[rr] = 0.f;

    const float* wrow = W + (size_t)col * DIN;
    for (int d = 0; d < DIN; d += 4) {
        float4 wv = *(const float4*)(wrow + d);
#pragma unroll
        for (int rr = 0; rr < 16; rr++) {
            const float* xr = &xl[(team * 16 + rr) * DIN + d];  // wave-uniform broadcast
            acc[rr] += xr[0] * wv.x + xr[1] * wv.y + xr[2] * wv.z + xr[3] * wv.w;
        }
    }
#pragma unroll
    for (int rr = 0; rr < 16; rr++)
        z16[(size_t)(row0 + rr) * DOUT + col] = f2bf(acc[rr]);
}

// ---------------------------------------------------------------------------
// Kernel 2 (512 thr, R7 verbatim): per-bucket adjacency build + extract.
//   Block mb owns rows [mb*32, mb*32+32) as a 32 KB LDS bitmask (diag
//   pre-folded). Reads its bucket slice from bucket[sb][mb][slot]
//   (128 chunks of 256 B) with 4 independent unconditional uint4 loads
//   per thread (validity via cnt), LDS atomicOr dedup, then popcount +
//   wave scan -> deg/dis/list.
// ---------------------------------------------------------------------------
__global__ __launch_bounds__(512) void gcn_build(const uint32_t* __restrict__ cnt,
                                                 const uint32_t* __restrict__ bucket,
                                                 float* __restrict__ dis,
                                                 int* __restrict__ deg,
                                                 uint16_t* __restrict__ list) {
    __shared__ uint32_t lm[BROWS * WPR];             // 32 KB
    __shared__ uint32_t cl[SCB];
    int t = threadIdx.x;
    int mb = blockIdx.x;
    int r0 = mb * BROWS;

    // init: zero + diagonal (diag word-in-row of row r0+r is mb, bit r)
    for (int w4 = t; w4 < BROWS * WPR / 4; w4 += 512) {
        uint32_t w0 = w4 * 4;
        uint32_t vals[4];
#pragma unroll
        for (int k = 0; k < 4; k++) {
            uint32_t w = w0 + k;
            uint32_t r = w >> 8;
            uint32_t wir = w & 255u;
            vals[k] = (wir == (uint32_t)mb) ? (1u << r) : 0u;
        }
        ((uint4*)lm)[w4] = make_uint4(vals[0], vals[1], vals[2], vals[3]);
    }
    if (t < SCB) cl[t] = min(cnt[(t << 8) + mb], (uint32_t)BCAP);
    __syncthreads();

    // gather bucket slice: 2048 uint4 total; i4 -> sb = i4>>4, q = i4&15
    const uint4* bk4 = (const uint4*)bucket;
#pragma unroll
    for (int j = 0; j < 4; j++) {
        int i4 = t + j * 512;
        int sb = i4 >> 4;
        int q  = i4 & 15;
        uint4 u = bk4[((size_t)sb << 12) + (mb << 4) + q];   // unconditional
        uint32_t uu[4] = {u.x, u.y, u.z, u.w};
#pragma unroll
        for (int c2 = 0; c2 < 4; c2++) {
            int slot = q * 4 + c2;
            if ((uint32_t)slot < cl[sb]) {
                uint32_t p = uu[c2];
                int row = p >> 13;
                int dst = p & 8191;
                atomicOr(&lm[row * WPR + (dst >> 5)], 1u << (dst & 31));
            }
        }
    }
    __syncthreads();

    // extract: 8 waves, 4 rows per wave. popcount + wave prefix scan
    int wave = t >> 6, lane = t & 63;
    for (int rr = 0; rr < BROWS / 8; rr++) {
        int r = wave * (BROWS / 8) + rr;
        int row = r0 + r;
        uint4 w = ((const uint4*)(lm + r * WPR))[lane];   // words 4*lane..4*lane+3
        uint32_t wa[4] = {w.x, w.y, w.z, w.w};
        int c = __popc(w.x) + __popc(w.y) + __popc(w.z) + __popc(w.w);

        int sum = c;                                 // inclusive wave scan (width 64)
        for (int off = 1; off < 64; off <<= 1) {
            int v = __shfl_up(sum, off, 64);
            if (lane >= off) sum += v;
        }
        int excl = sum - c;
        if (lane == 63) {
            deg[row] = sum;
            dis[row] = rsqrtf((float)sum + EPS);
        }

        uint16_t* lrow = list + (size_t)row * MAXDEG;
        int bbase = lane * 128;                      // first bit index of this lane
        int pos = excl;
#pragma unroll
        for (int k = 0; k < 4; k++) {
            uint32_t m = wa[k];
            while (m) {
                int b = __ffs(m) - 1;
                m &= m - 1;
                if (pos < MAXDEG) lrow[pos] = (uint16_t)(bbase + k * 32 + b);
                pos++;
            }
        }
    }
}

// ---------------------------------------------------------------------------
// Kernel 3 (R7 verbatim): out[i][c] = b[c] + dis_i * sum_j dis_j * z[j][c].
// One wave per row, 4 rows per block, 4 gathers in flight with wave-uniform
// zero-predication.
// ---------------------------------------------------------------------------
__global__ __launch_bounds__(256) void gcn_agg(const int* __restrict__ deg,
                                               const float* __restrict__ dis,
                                               const uint16_t* __restrict__ list,
                                               const uint16_t* __restrict__ z16,
                                               const float* __restrict__ bias,
                                               float* __restrict__ out) {
    int row  = blockIdx.x * 4 + (threadIdx.x >> 6);
    int lane = threadIdx.x & 63;
    int n = min(deg[row], MAXDEG);

    const uint16_t* lrow = list + (size_t)row * MAXDEG;
    int j0 = (lane < n)      ? lrow[lane]      : 0;
    int j1 = (64 + lane < n) ? lrow[64 + lane] : 0;
    float d0 = dis[j0];
    float d1 = dis[j1];

    const uint32_t* zu = (const uint32_t*)z16;
    float a0 = 0.f, a1 = 0.f, b0 = 0.f, b1 = 0.f;
    float c0 = 0.f, c1 = 0.f, e0 = 0.f, e1 = 0.f;
    int n0 = min(n, 64);
    for (int m = 0; m < n0; m += 4) {                // 4 gathers in flight
        int   ja = __shfl(j0, m, 64);     float wa_ = __shfl(d0, m, 64);
        int   jb = __shfl(j0, m + 1, 64); float wb_ = __shfl(d0, m + 1, 64);
        int   jc = __shfl(j0, m + 2, 64); float wc_ = __shfl(d0, m + 2, 64);
        int   jd = __shfl(j0, m + 3, 64); float wd_ = __shfl(d0, m + 3, 64);
        if (m + 1 >= n0) wb_ = 0.f;                  // wave-uniform predicates
        if (m + 2 >= n0) wc_ = 0.f;
        if (m + 3 >= n0) wd_ = 0.f;
        uint32_t ua = zu[(size_t)ja * 64 + lane];    // coalesced 256 B each
        uint32_t ub = zu[(size_t)jb * 64 + lane];
        uint32_t uc = zu[(size_t)jc * 64 + lane];
        uint32_t ud = zu[(size_t)jd * 64 + lane];
        a0 += wa_ * bf2f(ua & 0xffffu);  a1 += wa_ * bf2f(ua >> 16);
        b0 += wb_ * bf2f(ub & 0xffffu);  b1 += wb_ * bf2f(ub >> 16);
        c0 += wc_ * bf2f(uc & 0xffffu);  c1 += wc_ * bf2f(uc >> 16);
        e0 += wd_ * bf2f(ud & 0xffffu);  e1 += wd_ * bf2f(ud >> 16);
    }
    for (int m2 = 64; m2 < n; m2++) {                // rare (deg > 64)
        int   jb = __shfl(j1, m2 - 64, 64); float db = __shfl(d1, m2 - 64, 64);
        uint32_t ub = zu[(size_t)jb * 64 + lane];
        b0 += db * bf2f(ub & 0xffffu);
        b1 += db * bf2f(ub >> 16);
    }
    a0 += b0 + c0 + e0;
    a1 += b1 + c1 + e1;

    float di = dis[row];
    float2 bv = ((const float2*)bias)[lane];
    float2 o;
    o.x = bv.x + di * a0;
    o.y = bv.y + di * a1;
    ((float2*)out)[(size_t)row * 64 + lane] = o;
}

// ---------------------------------------------------------------------------
extern "C" void kernel_launch(void* const* d_in, const int* in_sizes, int n_in,
                              void* d_out, int out_size, void* d_ws, size_t ws_size,
                              hipStream_t stream) {
    const float* x  = (const float*)d_in[0];
    const int*   ei = (const int*)d_in[1];
    const float* W  = (const float*)d_in[2];
    const float* b  = (const float*)d_in[3];
    float* out = (float*)d_out;

    int E = in_sizes[1] / 2;

    float*    dis    = (float*)   d_ws;
    int*      deg    = (int*)     ((char*)d_ws + OFF_DEG);
    uint16_t* list   = (uint16_t*)((char*)d_ws + OFF_LIST);
    uint16_t* z16    = (uint16_t*)((char*)d_ws + OFF_Z16);
    uint32_t* cnt    = (uint32_t*)((char*)d_ws + OFF_CNT);
    uint32_t* bucket = (uint32_t*)((char*)d_ws + OFF_BUCK);

    // edge bucket-scatter (LDS-staged, coalesced flush)  ||  x@W^T
    gcn_scatter_xw<<<SCB + XWB, 512, 0, stream>>>(ei, E, x, W, z16, cnt, bucket);

    // per-bucket LDS bitmask build + extract
    gcn_build<<<NB, 512, 0, stream>>>(cnt, bucket, dis, deg, list);

    gcn_agg<<<N_NODES / 4, 256, 0, stream>>>(deg, dis, list, z16, b, out);
}

// Round 10
// 91.692 us; speedup vs baseline: 1.0499x; 1.0499x over previous
//
#include <hip/hip_runtime.h>
#include <cstdint>

#define N_NODES 8192
#define DIN 128
#define DOUT 128
#define MAXDEG 128                               // Poisson(32): P(deg>128) ~ 1e-18
#define EPS 1e-8f

#define NB 256                                   // buckets == build blocks
#define BROWS 32                                 // adjacency rows per bucket/build block
#define WPR 256                                  // u32 words per adjacency row (8192/32)
#define SCB 128                                  // scatter blocks
#define BCAP 64                                  // slots per (scatter block, bucket); mean 16
#define STAGE_WORDS (NB * BCAP)                  // 16384 u32 = 64 KB LDS stage
#define XWB 256                                  // xw blocks
#define XW_ROWS 32                               // rows per xw block

// workspace layout (bytes):
// [dis 32K][deg 32K][list 2M][z16 2M][cnt 128K][bucket 8M]
#define OFF_DEG   (N_NODES * 4)
#define OFF_LIST  (OFF_DEG + N_NODES * 4)
#define OFF_Z16   (OFF_LIST + N_NODES * MAXDEG * 2)
#define OFF_CNT   (OFF_Z16 + N_NODES * DOUT * 2)
#define OFF_BUCK  (OFF_CNT + SCB * NB * 4)

static __device__ __forceinline__ uint16_t f2bf(float f) {
    uint32_t u = __float_as_uint(f);
    return (uint16_t)((u + 0x7fffu + ((u >> 16) & 1u)) >> 16);   // RNE
}
static __device__ __forceinline__ float bf2f(uint32_t bits16) {
    return __uint_as_float(bits16 << 16);
}

// ---------------------------------------------------------------------------
// Kernel 1: blocks [0,128): edge bucket-scatter, LDS-STAGED.
//   Rank via LDS returning-atomicAdd into a [256][64] LDS stage, then one
//   fully-coalesced 64 KB linear flush to bucket[sb][bucket][slot].
//   Garbage slots are masked downstream by cnt.
// blocks [128,384): z16 = bf16(x @ W^T), 32 rows per block (4 column-teams).
// [R7 bytes — best measured configuration, 92.50 µs / 92.54 µs twin]
// ---------------------------------------------------------------------------
__global__ __launch_bounds__(512) void gcn_scatter_xw(const int* __restrict__ ei, int E,
                                                      const float* __restrict__ x,
                                                      const float* __restrict__ W,
                                                      uint16_t* __restrict__ z16,
                                                      uint32_t* __restrict__ cnt,
                                                      uint32_t* __restrict__ bucket) {
    __shared__ uint32_t shbuf[STAGE_WORDS + NB];     // 64 KB stage | 1 KB hist
    int t = threadIdx.x;

    if ((int)blockIdx.x < SCB) {
        // ---------------- scatter role ----------------
        int sb = blockIdx.x;
        uint32_t* stage = shbuf;                     // [NB][BCAP]
        uint32_t* hist  = shbuf + STAGE_WORDS;       // [NB]
        if (t < NB) hist[t] = 0;
        __syncthreads();

        const int4* s4 = (const int4*)ei;
        const int4* d4 = (const int4*)(ei + E);
        int nIter = E >> 2;

#define SC1(ss, dd) do { unsigned b_ = ((unsigned)(ss)) >> 5;                              \
            unsigned r_ = atomicAdd(&hist[b_], 1u);                                        \
            if (r_ < BCAP) stage[(b_ << 6) + r_] =                                         \
                (((unsigned)(ss) & 31u) << 13) | (unsigned)(dd); } while (0)

        for (int g = sb * 512 + t; g < nIter; g += SCB * 512) {   // exactly 1 iter here
            int4 vs = s4[g], vd = d4[g];
            SC1(vs.x, vd.x); SC1(vs.y, vd.y); SC1(vs.z, vd.z); SC1(vs.w, vd.w);
        }
        if (sb == 0) {                                            // scalar tail (E % 4)
            for (int i = (nIter << 2) + t; i < E; i += 512) {
                int ss = ei[i], dd = ei[E + i];
                SC1(ss, dd);
            }
        }
#undef SC1
        __syncthreads();

        // coalesced 64 KB flush: bucket[sb * 16384 + s], s linear
        const uint4* st4 = (const uint4*)stage;
        uint4* gb4 = (uint4*)(bucket + ((size_t)sb << 14));
        for (int i = t; i < STAGE_WORDS / 4; i += 512)
            gb4[i] = st4[i];
        if (t < NB) cnt[(sb << 8) + t] = hist[t];
        return;
    }

    // ---------------- xw role: 4 column-teams of 128; team does 8 rows ----
    int bb = blockIdx.x - SCB;
    int col = t & 127;
    int team = t >> 7;                               // 0..3
    int row0 = bb * XW_ROWS + team * 8;
    float* xl = (float*)shbuf;                       // [32][128] = 16 KB subset

    for (int rr = 0; rr < 8; rr++)
        xl[(team * 8 + rr) * DIN + col] = x[(size_t)(row0 + rr) * DIN + col];
    __syncthreads();

    float acc[8];
#pragma unroll
    for (int rr = 0; rr < 8; rr++) acc[rr] = 0.f;

    const float* wrow = W + (size_t)col * DIN;
    for (int d = 0; d < DIN; d += 4) {
        float4 wv = *(const float4*)(wrow + d);
#pragma unroll
        for (int rr = 0; rr < 8; rr++) {
            const float* xr = &xl[(team * 8 + rr) * DIN + d];   // wave-uniform broadcast
            acc[rr] += xr[0] * wv.x + xr[1] * wv.y + xr[2] * wv.z + xr[3] * wv.w;
        }
    }
#pragma unroll
    for (int rr = 0; rr < 8; rr++)
        z16[(size_t)(row0 + rr) * DOUT + col] = f2bf(acc[rr]);
}

// ---------------------------------------------------------------------------
// Kernel 2: per-bucket adjacency build + extract. Block mb owns rows
//   [mb*32, mb*32+32) as a 32 KB LDS bitmask (diag pre-folded into init).
//   Reads its bucket slice from the transposed layout bucket[sb][mb][slot]
//   (128 chunks of 256 B) with 4 independent unconditional uint4 loads per
//   thread (validity via cnt), LDS atomicOr dedup, then popcount + wave
//   scan -> deg/dis/list.
// ---------------------------------------------------------------------------
__global__ __launch_bounds__(512) void gcn_build(const uint32_t* __restrict__ cnt,
                                                 const uint32_t* __restrict__ bucket,
                                                 float* __restrict__ dis,
                                                 int* __restrict__ deg,
                                                 uint16_t* __restrict__ list) {
    __shared__ uint32_t lm[BROWS * WPR];             // 32 KB
    __shared__ uint32_t cl[SCB];
    int t = threadIdx.x;
    int mb = blockIdx.x;
    int r0 = mb * BROWS;

    // init: zero + diagonal (diag word-in-row of row r0+r is mb, bit r)
    for (int w4 = t; w4 < BROWS * WPR / 4; w4 += 512) {
        uint32_t w0 = w4 * 4;
        uint32_t vals[4];
#pragma unroll
        for (int k = 0; k < 4; k++) {
            uint32_t w = w0 + k;
            uint32_t r = w >> 8;
            uint32_t wir = w & 255u;
            vals[k] = (wir == (uint32_t)mb) ? (1u << r) : 0u;
        }
        ((uint4*)lm)[w4] = make_uint4(vals[0], vals[1], vals[2], vals[3]);
    }
    if (t < SCB) cl[t] = min(cnt[(t << 8) + mb], (uint32_t)BCAP);
    __syncthreads();

    // gather bucket slice: 2048 uint4 total; i4 -> sb = i4>>4, q = i4&15
    const uint4* bk4 = (const uint4*)bucket;
#pragma unroll
    for (int j = 0; j < 4; j++) {
        int i4 = t + j * 512;
        int sb = i4 >> 4;
        int q  = i4 & 15;
        uint4 u = bk4[((size_t)sb << 12) + (mb << 4) + q];   // unconditional
        uint32_t uu[4] = {u.x, u.y, u.z, u.w};
#pragma unroll
        for (int c2 = 0; c2 < 4; c2++) {
            int slot = q * 4 + c2;
            if ((uint32_t)slot < cl[sb]) {
                uint32_t p = uu[c2];
                int row = p >> 13;
                int dst = p & 8191;
                atomicOr(&lm[row * WPR + (dst >> 5)], 1u << (dst & 31));
            }
        }
    }
    __syncthreads();

    // extract: 8 waves, 4 rows per wave. popcount + wave prefix scan
    int wave = t >> 6, lane = t & 63;
    for (int rr = 0; rr < BROWS / 8; rr++) {
        int r = wave * (BROWS / 8) + rr;
        int row = r0 + r;
        uint4 w = ((const uint4*)(lm + r * WPR))[lane];   // words 4*lane..4*lane+3
        uint32_t wa[4] = {w.x, w.y, w.z, w.w};
        int c = __popc(w.x) + __popc(w.y) + __popc(w.z) + __popc(w.w);

        int sum = c;                                 // inclusive wave scan (width 64)
        for (int off = 1; off < 64; off <<= 1) {
            int v = __shfl_up(sum, off, 64);
            if (lane >= off) sum += v;
        }
        int excl = sum - c;
        if (lane == 63) {
            deg[row] = sum;
            dis[row] = rsqrtf((float)sum + EPS);
        }

        uint16_t* lrow = list + (size_t)row * MAXDEG;
        int bbase = lane * 128;                      // first bit index of this lane
        int pos = excl;
#pragma unroll
        for (int k = 0; k < 4; k++) {
            uint32_t m = wa[k];
            while (m) {
                int b = __ffs(m) - 1;
                m &= m - 1;
                if (pos < MAXDEG) lrow[pos] = (uint16_t)(bbase + k * 32 + b);
                pos++;
            }
        }
    }
}

// ---------------------------------------------------------------------------
// Kernel 3: out[i][c] = b[c] + dis_i * sum_{j in row i} dis_j * z[j][c]
// (self loop is already in the list). One wave per row, 4 rows per block.
// 4 gathers in flight with wave-uniform zero-predication.
// ---------------------------------------------------------------------------
__global__ __launch_bounds__(256) void gcn_agg(const int* __restrict__ deg,
                                               const float* __restrict__ dis,
                                               const uint16_t* __restrict__ list,
                                               const uint16_t* __restrict__ z16,
                                               const float* __restrict__ bias,
                                               float* __restrict__ out) {
    int row  = blockIdx.x * 4 + (threadIdx.x >> 6);
    int lane = threadIdx.x & 63;
    int n = min(deg[row], MAXDEG);

    const uint16_t* lrow = list + (size_t)row * MAXDEG;
    int j0 = (lane < n)      ? lrow[lane]      : 0;
    int j1 = (64 + lane < n) ? lrow[64 + lane] : 0;
    float d0 = dis[j0];
    float d1 = dis[j1];

    const uint32_t* zu = (const uint32_t*)z16;
    float a0 = 0.f, a1 = 0.f, b0 = 0.f, b1 = 0.f;
    float c0 = 0.f, c1 = 0.f, e0 = 0.f, e1 = 0.f;
    int n0 = min(n, 64);
    for (int m = 0; m < n0; m += 4) {                // 4 gathers in flight
        int   ja = __shfl(j0, m, 64);     float wa_ = __shfl(d0, m, 64);
        int   jb = __shfl(j0, m + 1, 64); float wb_ = __shfl(d0, m + 1, 64);
        int   jc = __shfl(j0, m + 2, 64); float wc_ = __shfl(d0, m + 2, 64);
        int   jd = __shfl(j0, m + 3, 64); float wd_ = __shfl(d0, m + 3, 64);
        if (m + 1 >= n0) wb_ = 0.f;                  // wave-uniform predicates
        if (m + 2 >= n0) wc_ = 0.f;
        if (m + 3 >= n0) wd_ = 0.f;
        uint32_t ua = zu[(size_t)ja * 64 + lane];    // coalesced 256 B each
        uint32_t ub = zu[(size_t)jb * 64 + lane];
        uint32_t uc = zu[(size_t)jc * 64 + lane];
        uint32_t ud = zu[(size_t)jd * 64 + lane];
        a0 += wa_ * bf2f(ua & 0xffffu);  a1 += wa_ * bf2f(ua >> 16);
        b0 += wb_ * bf2f(ub & 0xffffu);  b1 += wb_ * bf2f(ub >> 16);
        c0 += wc_ * bf2f(uc & 0xffffu);  c1 += wc_ * bf2f(uc >> 16);
        e0 += wd_ * bf2f(ud & 0xffffu);  e1 += wd_ * bf2f(ud >> 16);
    }
    for (int m2 = 64; m2 < n; m2++) {                // rare (deg > 64)
        int   jb = __shfl(j1, m2 - 64, 64); float db = __shfl(d1, m2 - 64, 64);
        uint32_t ub = zu[(size_t)jb * 64 + lane];
        b0 += db * bf2f(ub & 0xffffu);
        b1 += db * bf2f(ub >> 16);
    }
    a0 += b0 + c0 + e0;
    a1 += b1 + c1 + e1;

    float di = dis[row];
    float2 bv = ((const float2*)bias)[lane];
    float2 o;
    o.x = bv.x + di * a0;
    o.y = bv.y + di * a1;
    ((float2*)out)[(size_t)row * 64 + lane] = o;
}

// ---------------------------------------------------------------------------
extern "C" void kernel_launch(void* const* d_in, const int* in_sizes, int n_in,
                              void* d_out, int out_size, void* d_ws, size_t ws_size,
                              hipStream_t stream) {
    const float* x  = (const float*)d_in[0];
    const int*   ei = (const int*)d_in[1];
    const float* W  = (const float*)d_in[2];
    const float* b  = (const float*)d_in[3];
    float* out = (float*)d_out;

    int E = in_sizes[1] / 2;

    float*    dis    = (float*)   d_ws;
    int*      deg    = (int*)     ((char*)d_ws + OFF_DEG);
    uint16_t* list   = (uint16_t*)((char*)d_ws + OFF_LIST);
    uint16_t* z16    = (uint16_t*)((char*)d_ws + OFF_Z16);
    uint32_t* cnt    = (uint32_t*)((char*)d_ws + OFF_CNT);
    uint32_t* bucket = (uint32_t*)((char*)d_ws + OFF_BUCK);

    // edge bucket-scatter (LDS-staged, coalesced flush)  ||  x@W^T
    gcn_scatter_xw<<<SCB + XWB, 512, 0, stream>>>(ei, E, x, W, z16, cnt, bucket);

    // per-bucket LDS bitmask build + extract
    gcn_build<<<NB, 512, 0, stream>>>(cnt, bucket, dis, deg, list);

    gcn_agg<<<N_NODES / 4, 256, 0, stream>>>(deg, dis, list, z16, b, out);
}